// Round 5
// baseline (542.293 us; speedup 1.0000x reference)
//
#include <hip/hip_runtime.h>

// GCN on 1M nodes / 16M edges, collapsed to scalar per-node features.
//
//   deg[c]  = sum_{e: col=c} ew[e] + 1 (self loop)
//   dis     = rsqrt(deg)
//   S1[c]   = dis[c] * (sum_e dis[row]*ew*x[row]) + dis[c]^2 * x[c]
//   g[c]    = sum_j relu(S1[c]*W1[j] + b1[j]) * W2[j]
//   S2[c]   = dis[c] * (sum_e dis[row]*ew*g[row]) + dis[c]^2 * g[c]
//   y[c]    = sigmoid((S2[c]+b2)*Wl + bl)
//
// R4 post-mortem: k_acc mode-1 bound by random p[row] gathers (16M x 64B
// cacheline fetches) thrashed out of L2 by the 128MB rec stream; k_fill at
// 48% occupancy (31.7KB LDS).
// R5: nontemporal streams, bf16 gather table (2MB, L2-resident), EPT=8 fill,
// k_acc split=4 with 512-thread blocks.

constexpr int N_NODES = 1000000;
constexpr int N_EDGES = 16000000;

constexpr int BSHIFT = 12;
constexpr int BNODES = 1 << BSHIFT;                    // 4096 nodes/bucket
constexpr int NB = (N_NODES + BNODES - 1) / BNODES;    // 245 buckets
constexpr int EPT = 8;                                 // edges/thread (pairs of 2)
constexpr int PAIRS = EPT / 2;                         // 4
constexpr int FBLK = 256;
constexpr int CHUNK = FBLK * EPT;                      // 2048 edges/block
constexpr int NBLK = (N_EDGES + CHUNK - 1) / CHUNK;    // 7813
constexpr int NHIST = NB * NBLK;                       // 1,914,185
constexpr int SCAN_TPB = 256;
constexpr int SCAN_EPB = 1024;
constexpr int NSCAN = (NHIST + SCAN_EPB - 1) / SCAN_EPB;  // 1870
constexpr int NHIST_PAD = NSCAN * SCAN_EPB;

__device__ inline unsigned short f2bf(float f) {   // fp32 -> bf16 RNE
  unsigned u = __float_as_uint(f);
  return (unsigned short)((u + 0x7FFFu + ((u >> 16) & 1u)) >> 16);
}
__device__ inline float bf2f(unsigned short h) {
  return __uint_as_float((unsigned)h << 16);
}

// ---------------- build: count / scan / fill ----------------

__global__ __launch_bounds__(FBLK) void k_count(const int* __restrict__ col,
                                                unsigned* __restrict__ hist) {
  __shared__ unsigned cnt[256];
  int t = threadIdx.x;
  cnt[t] = 0;
  __syncthreads();
  int e0 = blockIdx.x * CHUNK;
#pragma unroll
  for (int k = 0; k < PAIRS; ++k) {
    int e = e0 + (k * FBLK + t) * 2;
    if (e < N_EDGES) {   // N_EDGES even => e+1 also valid
      long long cc = __builtin_nontemporal_load((const long long*)(col + e));
      int c0 = (int)(unsigned)cc, c1 = (int)(unsigned)(cc >> 32);
      atomicAdd(&cnt[c0 >> BSHIFT], 1u);
      atomicAdd(&cnt[c1 >> BSHIFT], 1u);
    }
  }
  __syncthreads();
  if (t < NB) hist[(size_t)t * NBLK + blockIdx.x] = cnt[t];
}

// Flat exclusive scan of hist (bucket-major => values ARE the global
// (bucket,block) record offsets; hist[b*NBLK] is bucket b's base).
__global__ __launch_bounds__(SCAN_TPB) void k_scanA(unsigned* __restrict__ h,
                                                    unsigned* __restrict__ bsum) {
  __shared__ unsigned sc[SCAN_TPB];
  int t = threadIdx.x;
  size_t base = (size_t)blockIdx.x * SCAN_EPB + (size_t)t * 4;
  uint4 v = *(const uint4*)(h + base);
  unsigned s = v.x + v.y + v.z + v.w;
  sc[t] = s;
  __syncthreads();
  for (int d = 1; d < SCAN_TPB; d <<= 1) {
    unsigned u = (t >= d) ? sc[t - d] : 0;
    __syncthreads();
    sc[t] += u;
    __syncthreads();
  }
  unsigned ex = sc[t] - s;
  uint4 o;
  o.x = ex; o.y = ex + v.x; o.z = ex + v.x + v.y; o.w = ex + v.x + v.y + v.z;
  *(uint4*)(h + base) = o;
  if (t == SCAN_TPB - 1) bsum[blockIdx.x] = sc[t];
}

__global__ __launch_bounds__(1024) void k_scanB(unsigned* __restrict__ bsum) {
  __shared__ unsigned sc[1024];
  int t = threadIdx.x;
  unsigned a0 = (2 * t < NSCAN) ? bsum[2 * t] : 0;
  unsigned a1 = (2 * t + 1 < NSCAN) ? bsum[2 * t + 1] : 0;
  unsigned s = a0 + a1;
  sc[t] = s;
  __syncthreads();
  for (int d = 1; d < 1024; d <<= 1) {
    unsigned u = (t >= d) ? sc[t - d] : 0;
    __syncthreads();
    sc[t] += u;
    __syncthreads();
  }
  unsigned ex = sc[t] - s;
  if (2 * t < NSCAN) bsum[2 * t] = ex;
  if (2 * t + 1 < NSCAN) bsum[2 * t + 1] = ex + a0;
}

__global__ __launch_bounds__(SCAN_TPB) void k_scanC(unsigned* __restrict__ h,
                                                    const unsigned* __restrict__ bsum) {
  unsigned add = bsum[blockIdx.x];
  size_t base = (size_t)blockIdx.x * SCAN_EPB + (size_t)threadIdx.x * 4;
  uint4 v = *(uint4*)(h + base);
  v.x += add; v.y += add; v.z += add; v.w += add;
  *(uint4*)(h + base) = v;
}

// Register-stash + LDS-reorder fill: coalesced nontemporal record writes.
// record = (row<<12 | col&0xFFF, bits(ew)); row < 2^20 fits.
__global__ __launch_bounds__(FBLK) void k_fill(const int* __restrict__ row,
                                               const int* __restrict__ col,
                                               const float* __restrict__ ew,
                                               const unsigned* __restrict__ hist,
                                               uint2* __restrict__ rec) {
  __shared__ unsigned lhist[256];
  __shared__ unsigned lb[256];
  __shared__ unsigned tail[256];
  __shared__ unsigned gbase[NB];
  __shared__ uint2 stage[CHUNK];
  __shared__ unsigned char sbkt[CHUNK];

  int t = threadIdx.x;
  int blk = blockIdx.x;
  lhist[t] = 0;
  for (int i = t; i < NB; i += FBLK) gbase[i] = hist[(size_t)i * NBLK + blk];
  __syncthreads();

  int e0 = blk * CHUNK;
  unsigned pk[EPT], wv[EPT];
  int bk[EPT];
#pragma unroll
  for (int k = 0; k < PAIRS; ++k) {
    int e = e0 + (k * FBLK + t) * 2;
    bk[2 * k] = bk[2 * k + 1] = -1;
    if (e < N_EDGES) {
      long long cc = __builtin_nontemporal_load((const long long*)(col + e));
      long long rr = __builtin_nontemporal_load((const long long*)(row + e));
      long long ww = __builtin_nontemporal_load((const long long*)(ew + e));
      int c0 = (int)(unsigned)cc, c1 = (int)(unsigned)(cc >> 32);
      int r0 = (int)(unsigned)rr, r1 = (int)(unsigned)(rr >> 32);
      pk[2 * k]     = ((unsigned)r0 << BSHIFT) | (unsigned)(c0 & (BNODES - 1));
      pk[2 * k + 1] = ((unsigned)r1 << BSHIFT) | (unsigned)(c1 & (BNODES - 1));
      wv[2 * k]     = (unsigned)cc ? (unsigned)ww : (unsigned)ww;  // placeholder
      wv[2 * k]     = (unsigned)(unsigned long long)ww;
      wv[2 * k + 1] = (unsigned)((unsigned long long)ww >> 32);
      bk[2 * k]     = c0 >> BSHIFT;
      bk[2 * k + 1] = c1 >> BSHIFT;
      atomicAdd(&lhist[bk[2 * k]], 1u);
      atomicAdd(&lhist[bk[2 * k + 1]], 1u);
    }
  }
  __syncthreads();

  unsigned own = lhist[t];
  lb[t] = own;
  __syncthreads();
  for (int d = 1; d < 256; d <<= 1) {   // Hillis-Steele inclusive
    unsigned u = (t >= d) ? lb[t - d] : 0;
    __syncthreads();
    lb[t] += u;
    __syncthreads();
  }
  unsigned total = lb[255];
  unsigned ex = lb[t] - own;
  __syncthreads();
  lb[t] = ex;
  tail[t] = ex;
  __syncthreads();

#pragma unroll
  for (int k = 0; k < EPT; ++k) {
    if (bk[k] >= 0) {
      unsigned s = atomicAdd(&tail[bk[k]], 1u);
      stage[s] = make_uint2(pk[k], wv[k]);
      sbkt[s] = (unsigned char)bk[k];
    }
  }
  __syncthreads();

  // staged order is bucket-sorted: consecutive s -> consecutive global dest
  for (unsigned s = t; s < total; s += FBLK) {
    unsigned b = sbkt[s];
    uint2 v = stage[s];
    unsigned long long packed = (unsigned long long)v.x |
                                ((unsigned long long)v.y << 32);
    __builtin_nontemporal_store(packed,
        (unsigned long long*)&rec[gbase[b] + (s - lb[b])]);
  }
}

// ---------------- accumulate: one (bucket,part) per block ----------------
// mode 0: val = ew (weighted degree). mode 1: val = ew * bf16 p[row].
__global__ __launch_bounds__(512) void k_acc(const uint2* __restrict__ rec,
                                             const unsigned* __restrict__ hist,
                                             const unsigned short* __restrict__ p16,
                                             float* __restrict__ out,
                                             int mode, int split) {
  __shared__ float acc[BNODES];
  for (int i = threadIdx.x; i < BNODES; i += 512) acc[i] = 0.f;
  __syncthreads();
  int b = blockIdx.x / split;
  int part = blockIdx.x - b * split;
  unsigned bs = hist[(size_t)b * NBLK];
  unsigned be = (b + 1 < NB) ? hist[(size_t)(b + 1) * NBLK] : (unsigned)N_EDGES;
  unsigned len = be - bs;
  unsigned s = bs + (unsigned)(((unsigned long long)len * part) / split);
  unsigned e = bs + (unsigned)(((unsigned long long)len * (part + 1)) / split);

  unsigned i = s + threadIdx.x;
  for (; i + 7u * 512u < e; i += 8u * 512u) {   // 8 records in flight
    unsigned long long r[8];
#pragma unroll
    for (int j = 0; j < 8; ++j)
      r[j] = __builtin_nontemporal_load(
          (const unsigned long long*)&rec[i + (unsigned)j * 512u]);
    float v[8];
#pragma unroll
    for (int j = 0; j < 8; ++j) {
      v[j] = __uint_as_float((unsigned)(r[j] >> 32));
      if (mode) v[j] *= bf2f(p16[(unsigned)r[j] >> BSHIFT]);
    }
#pragma unroll
    for (int j = 0; j < 8; ++j)
      atomicAdd(&acc[(unsigned)r[j] & (BNODES - 1)], v[j]);
  }
  for (; i < e; i += 512u) {
    unsigned long long r = __builtin_nontemporal_load(
        (const unsigned long long*)&rec[i]);
    float v = __uint_as_float((unsigned)(r >> 32));
    if (mode) v *= bf2f(p16[(unsigned)r >> BSHIFT]);
    atomicAdd(&acc[(unsigned)r & (BNODES - 1)], v);
  }
  __syncthreads();

  float* o = out + (size_t)part * N_NODES;
  int base = b * BNODES;
  for (int j = threadIdx.x; j < BNODES && base + j < N_NODES; j += 512)
    o[base + j] = acc[j];
}

// ---------------- node-wise kernels ----------------

__global__ void k_dis_p(const float* __restrict__ x, const float* __restrict__ D,
                        float* __restrict__ A, unsigned short* __restrict__ P16,
                        int split) {
  int i = blockIdx.x * blockDim.x + threadIdx.x;
  if (i >= N_NODES) return;
  float deg = 1.0f;                       // self loop
  for (int j = 0; j < split; ++j) deg += D[(size_t)j * N_NODES + i];
  float d = rsqrtf(deg);
  A[i] = d;
  P16[i] = f2bf(d * x[i]);
}

__global__ void k_g2(const float* __restrict__ A, const float* __restrict__ x,
                     const float* __restrict__ D, unsigned short* __restrict__ P16,
                     const float* __restrict__ W1, const float* __restrict__ b1,
                     const float* __restrict__ W2, int split) {
  int i = blockIdx.x * blockDim.x + threadIdx.x;
  if (i >= N_NODES) return;
  float d = A[i];
  float sraw = 0.f;
  for (int j = 0; j < split; ++j) sraw += D[(size_t)j * N_NODES + i];
  float s1 = d * sraw + d * d * x[i];
  float g = 0.f;
#pragma unroll
  for (int j = 0; j < 4; ++j) {
    float h = fmaf(s1, W1[j], b1[j]);
    g = fmaf(fmaxf(h, 0.f), W2[j], g);
  }
  P16[i] = f2bf(d * g);
}

__global__ void k_out2(const float* __restrict__ A,
                       const unsigned short* __restrict__ P16,
                       const float* __restrict__ D, const float* __restrict__ b2,
                       const float* __restrict__ Wl, const float* __restrict__ bl,
                       float* __restrict__ y, int split) {
  int i = blockIdx.x * blockDim.x + threadIdx.x;
  if (i >= N_NODES) return;
  float d = A[i];
  float g = bf2f(P16[i]) / d;             // d in (0,1], safe
  float sraw = 0.f;
  for (int j = 0; j < split; ++j) sraw += D[(size_t)j * N_NODES + i];
  float agg2 = d * sraw + d * d * g;
  float v = fmaf(agg2 + b2[0], Wl[0], bl[0]);
  y[i] = 1.0f / (1.0f + expf(-v));
}

// ---------------- fallback (round-2 global-atomic path) ----------------

__global__ void f_deg(const int* __restrict__ col, const float* __restrict__ ew,
                      float* __restrict__ deg) {
  int i = blockIdx.x * blockDim.x + threadIdx.x;
  int stride = gridDim.x * blockDim.x;
  for (int e = i; e < N_EDGES; e += stride) atomicAdd(&deg[col[e]], ew[e]);
}
__global__ void f_dis(float* __restrict__ a) {
  int i = blockIdx.x * blockDim.x + threadIdx.x;
  if (i < N_NODES) a[i] = rsqrtf(a[i] + 1.0f);
}
__global__ void f_scatter(const int* __restrict__ row, const int* __restrict__ col,
                          const float* __restrict__ ew, const float* __restrict__ dis,
                          const float* __restrict__ src, float* __restrict__ acc) {
  int i = blockIdx.x * blockDim.x + threadIdx.x;
  int stride = gridDim.x * blockDim.x;
  for (int e = i; e < N_EDGES; e += stride) {
    int r = row[e]; int c = col[e];
    atomicAdd(&acc[c], dis[r] * ew[e] * src[r]);
  }
}
__global__ void f_g(const float* __restrict__ dis, const float* __restrict__ x,
                    float* __restrict__ s1g, const float* __restrict__ W1,
                    const float* __restrict__ b1, const float* __restrict__ W2) {
  int i = blockIdx.x * blockDim.x + threadIdx.x;
  if (i >= N_NODES) return;
  float d = dis[i];
  float s1 = d * s1g[i] + d * d * x[i];
  float g = 0.f;
#pragma unroll
  for (int j = 0; j < 4; ++j) {
    float h = fmaf(s1, W1[j], b1[j]);
    g = fmaf(fmaxf(h, 0.f), W2[j], g);
  }
  s1g[i] = g;
}
__global__ void f_out(const float* __restrict__ dis, const float* __restrict__ g,
                      float* __restrict__ s2out, const float* __restrict__ b2,
                      const float* __restrict__ Wl, const float* __restrict__ bl) {
  int i = blockIdx.x * blockDim.x + threadIdx.x;
  if (i >= N_NODES) return;
  float d = dis[i];
  float agg2 = d * s2out[i] + d * d * g[i];
  float v = fmaf(agg2 + b2[0], Wl[0], bl[0]);
  s2out[i] = 1.0f / (1.0f + expf(-v));
}

// ---------------- launch ----------------

extern "C" void kernel_launch(void* const* d_in, const int* in_sizes, int n_in,
                              void* d_out, int out_size, void* d_ws, size_t ws_size,
                              hipStream_t stream) {
  const float* x  = (const float*)d_in[0];
  const int* ei   = (const int*)d_in[1];   // int32 (harness narrows int64)
  const float* ew = (const float*)d_in[2];
  const float* W1 = (const float*)d_in[3];
  const float* b1 = (const float*)d_in[4];
  const float* W2 = (const float*)d_in[5];
  const float* b2 = (const float*)d_in[6];
  const float* Wl = (const float*)d_in[7];
  const float* bl = (const float*)d_in[8];

  const int* row = ei;
  const int* col = ei + N_EDGES;

  const size_t REC_B  = (size_t)N_EDGES * 8;          // 134,217,728
  const size_t HIST_B = (size_t)NHIST_PAD * 4;        // 7,659,520
  const size_t BSUM_B = ((size_t)NSCAN * 4 + 255) & ~255ull;
  const size_t NODE_B = (size_t)N_NODES * 4;
  const size_t P16_B  = ((size_t)N_NODES * 2 + 255) & ~255ull;
  const size_t FIXED  = REC_B + HIST_B + BSUM_B + NODE_B + P16_B;  // + A + P16

  dim3 blk(256);
  dim3 ngrid((N_NODES + 255) / 256);

  int split = 0;
  for (int s : {4, 2, 1})
    if (ws_size >= FIXED + (size_t)s * NODE_B) { split = s; break; }

  if (split) {
    char* w = (char*)d_ws;
    uint2* rec           = (uint2*)w;
    unsigned* hist       = (unsigned*)(w + REC_B);
    unsigned* bsum       = (unsigned*)(w + REC_B + HIST_B);
    float* A             = (float*)(w + REC_B + HIST_B + BSUM_B);
    unsigned short* P16  = (unsigned short*)(A + N_NODES);
    float* D             = (float*)((char*)P16 + P16_B);  // split partials

    k_count<<<NBLK, FBLK, 0, stream>>>(col, hist);
    k_scanA<<<NSCAN, SCAN_TPB, 0, stream>>>(hist, bsum);
    k_scanB<<<1, 1024, 0, stream>>>(bsum);
    k_scanC<<<NSCAN, SCAN_TPB, 0, stream>>>(hist, bsum);
    k_fill <<<NBLK, FBLK, 0, stream>>>(row, col, ew, hist, rec);

    k_acc  <<<NB * split, 512, 0, stream>>>(rec, hist, nullptr, D, 0, split);
    k_dis_p<<<ngrid, blk, 0, stream>>>(x, D, A, P16, split);
    k_acc  <<<NB * split, 512, 0, stream>>>(rec, hist, P16, D, 1, split);
    k_g2   <<<ngrid, blk, 0, stream>>>(A, x, D, P16, W1, b1, W2, split);
    k_acc  <<<NB * split, 512, 0, stream>>>(rec, hist, P16, D, 1, split);
    k_out2 <<<ngrid, blk, 0, stream>>>(A, P16, D, b2, Wl, bl, (float*)d_out, split);
  } else {
    float* Aw = (float*)d_ws;
    float* Bw = Aw + N_NODES;
    float* Cw = (float*)d_out;
    hipMemsetAsync(d_ws, 0, 2ull * NODE_B, stream);
    hipMemsetAsync(d_out, 0, NODE_B, stream);
    dim3 egrid(4096);
    f_deg<<<egrid, blk, 0, stream>>>(col, ew, Aw);
    f_dis<<<ngrid, blk, 0, stream>>>(Aw);
    f_scatter<<<egrid, blk, 0, stream>>>(row, col, ew, Aw, x, Bw);
    f_g<<<ngrid, blk, 0, stream>>>(Aw, x, Bw, W1, b1, W2);
    f_scatter<<<egrid, blk, 0, stream>>>(row, col, ew, Aw, Bw, Cw);
    f_out<<<ngrid, blk, 0, stream>>>(Aw, Bw, Cw, b2, Wl, bl);
  }
}

// Round 6
// 495.566 us; speedup vs baseline: 1.0943x; 1.0943x over previous
//
#include <hip/hip_runtime.h>

// GCN on 1M nodes / 16M edges, collapsed to scalar per-node features.
//
//   deg[c]  = sum_{e: col=c} ew[e] + 1 (self loop)
//   dis     = rsqrt(deg)
//   S1[c]   = dis[c] * (sum_e dis[row]*ew*x[row]) + dis[c]^2 * x[c]
//   g[c]    = sum_j relu(S1[c]*W1[j] + b1[j]) * W2[j]
//   S2[c]   = dis[c] * (sum_e dis[row]*ew*g[row]) + dis[c]^2 * g[c]
//   y[c]    = sigmoid((S2[c]+b2)*Wl + bl)
//
// R5 post-mortem: CHUNK=2048 shortened bucket runs (write amp 155->175MB) and
// grew NBLK (more strided gbase reads + bigger hist). Occupancy was not the
// binding resource. k_acc mode-1 is divergent-gather transaction-bound.
// R6: revert fill to CHUNK=3072; transpose hist so count writes and fill
// reads are coalesced; keep bf16 gather table + nontemporal rec stream.

constexpr int N_NODES = 1000000;
constexpr int N_EDGES = 16000000;

constexpr int BSHIFT = 12;
constexpr int BNODES = 1 << BSHIFT;                    // 4096 nodes/bucket
constexpr int NB = (N_NODES + BNODES - 1) / BNODES;    // 245 buckets
constexpr int EPT = 12;                                // edges/thread in count+fill
constexpr int FBLK = 256;
constexpr int CHUNK = FBLK * EPT;                      // 3072 edges/block
constexpr int NBLK = (N_EDGES + CHUNK - 1) / CHUNK;    // 5209
constexpr int NHIST = NB * NBLK;                       // 1,276,205
constexpr int SCAN_TPB = 256;
constexpr int SCAN_EPB = 1024;
constexpr int NSCAN = (NHIST + SCAN_EPB - 1) / SCAN_EPB;  // 1247
constexpr int NHIST_PAD = NSCAN * SCAN_EPB;            // 1,276,928

__device__ inline unsigned short f2bf(float f) {   // fp32 -> bf16 RNE
  unsigned u = __float_as_uint(f);
  return (unsigned short)((u + 0x7FFFu + ((u >> 16) & 1u)) >> 16);
}
__device__ inline float bf2f(unsigned short h) {
  return __uint_as_float((unsigned)h << 16);
}

// ---------------- build: count / transpose / scan / transpose / fill --------

// histT layout [NBLK][256]: block writes its own contiguous row (coalesced).
__global__ __launch_bounds__(FBLK) void k_count(const int* __restrict__ col,
                                                unsigned* __restrict__ histT) {
  __shared__ unsigned cnt[256];
  int t = threadIdx.x;
  cnt[t] = 0;
  __syncthreads();
  int e0 = blockIdx.x * CHUNK;
#pragma unroll
  for (int k = 0; k < EPT; ++k) {
    int e = e0 + k * FBLK + t;
    if (e < N_EDGES) atomicAdd(&cnt[col[e] >> BSHIFT], 1u);
  }
  __syncthreads();
  histT[(size_t)blockIdx.x * 256 + t] = cnt[t];
}

// histT[NBLK][256] -> hist[b*NBLK + blk] (bucket-major flat, for linear scan)
__global__ __launch_bounds__(1024) void k_t1(const unsigned* __restrict__ in,
                                             unsigned* __restrict__ out) {
  __shared__ unsigned tile[32][33];
  int bx = blockIdx.x * 32;   // blk base
  int by = blockIdx.y * 32;   // b base
  int tx = threadIdx.x, ty = threadIdx.y;
  int rblk = bx + ty;
  if (rblk < NBLK) tile[ty][tx] = in[(size_t)rblk * 256 + by + tx];
  __syncthreads();
  int wb = by + ty, wblk = bx + tx;
  if (wb < NB && wblk < NBLK) out[(size_t)wb * NBLK + wblk] = tile[tx][ty];
}

// hist offsets (bucket-major) -> histT2[blk*256 + b] (fill reads coalesced)
__global__ __launch_bounds__(1024) void k_t2(const unsigned* __restrict__ in,
                                             unsigned* __restrict__ out) {
  __shared__ unsigned tile[32][33];
  int bx = blockIdx.x * 32;   // blk base
  int by = blockIdx.y * 32;   // b base
  int tx = threadIdx.x, ty = threadIdx.y;
  int rb = by + ty, rblk = bx + tx;
  if (rb < NB && rblk < NBLK) tile[ty][tx] = in[(size_t)rb * NBLK + rblk];
  __syncthreads();
  int wblk = bx + ty, wb = by + tx;
  if (wblk < NBLK && wb < NB) out[(size_t)wblk * 256 + wb] = tile[tx][ty];
}

__global__ __launch_bounds__(SCAN_TPB) void k_scanA(unsigned* __restrict__ h,
                                                    unsigned* __restrict__ bsum) {
  __shared__ unsigned sc[SCAN_TPB];
  int t = threadIdx.x;
  size_t base = (size_t)blockIdx.x * SCAN_EPB + (size_t)t * 4;
  uint4 v = *(const uint4*)(h + base);
  unsigned s = v.x + v.y + v.z + v.w;
  sc[t] = s;
  __syncthreads();
  for (int d = 1; d < SCAN_TPB; d <<= 1) {
    unsigned u = (t >= d) ? sc[t - d] : 0;
    __syncthreads();
    sc[t] += u;
    __syncthreads();
  }
  unsigned ex = sc[t] - s;
  uint4 o;
  o.x = ex; o.y = ex + v.x; o.z = ex + v.x + v.y; o.w = ex + v.x + v.y + v.z;
  *(uint4*)(h + base) = o;
  if (t == SCAN_TPB - 1) bsum[blockIdx.x] = sc[t];
}

__global__ __launch_bounds__(1024) void k_scanB(unsigned* __restrict__ bsum) {
  __shared__ unsigned sc[1024];
  int t = threadIdx.x;
  unsigned a0 = (2 * t < NSCAN) ? bsum[2 * t] : 0;
  unsigned a1 = (2 * t + 1 < NSCAN) ? bsum[2 * t + 1] : 0;
  unsigned s = a0 + a1;
  sc[t] = s;
  __syncthreads();
  for (int d = 1; d < 1024; d <<= 1) {
    unsigned u = (t >= d) ? sc[t - d] : 0;
    __syncthreads();
    sc[t] += u;
    __syncthreads();
  }
  unsigned ex = sc[t] - s;
  if (2 * t < NSCAN) bsum[2 * t] = ex;
  if (2 * t + 1 < NSCAN) bsum[2 * t + 1] = ex + a0;
}

__global__ __launch_bounds__(SCAN_TPB) void k_scanC(unsigned* __restrict__ h,
                                                    const unsigned* __restrict__ bsum) {
  unsigned add = bsum[blockIdx.x];
  size_t base = (size_t)blockIdx.x * SCAN_EPB + (size_t)threadIdx.x * 4;
  uint4 v = *(uint4*)(h + base);
  v.x += add; v.y += add; v.z += add; v.w += add;
  *(uint4*)(h + base) = v;
}

// Register-stash + LDS-reorder fill: coalesced record writes.
// record = (row<<12 | col&0xFFF, bits(ew)); row < 2^20 fits.
__global__ __launch_bounds__(FBLK) void k_fill(const int* __restrict__ row,
                                               const int* __restrict__ col,
                                               const float* __restrict__ ew,
                                               const unsigned* __restrict__ histT2,
                                               uint2* __restrict__ rec) {
  __shared__ unsigned lhist[256];
  __shared__ unsigned lb[256];
  __shared__ unsigned tail[256];
  __shared__ unsigned gbase[NB];
  __shared__ uint2 stage[CHUNK];
  __shared__ unsigned char sbkt[CHUNK];

  int t = threadIdx.x;
  int blk = blockIdx.x;
  lhist[t] = 0;
  for (int i = t; i < NB; i += FBLK)
    gbase[i] = histT2[(size_t)blk * 256 + i];          // coalesced row read
  __syncthreads();

  int e0 = blk * CHUNK;
  unsigned pk[EPT], wv[EPT];
  int bk[EPT];
#pragma unroll
  for (int k = 0; k < EPT; ++k) {
    int e = e0 + k * FBLK + t;
    bk[k] = -1;
    if (e < N_EDGES) {
      int c = col[e];
      pk[k] = ((unsigned)row[e] << BSHIFT) | (unsigned)(c & (BNODES - 1));
      wv[k] = __float_as_uint(ew[e]);
      bk[k] = c >> BSHIFT;
      atomicAdd(&lhist[bk[k]], 1u);
    }
  }
  __syncthreads();

  unsigned own = lhist[t];
  lb[t] = own;
  __syncthreads();
  for (int d = 1; d < 256; d <<= 1) {   // Hillis-Steele inclusive
    unsigned u = (t >= d) ? lb[t - d] : 0;
    __syncthreads();
    lb[t] += u;
    __syncthreads();
  }
  unsigned total = lb[255];
  unsigned ex = lb[t] - own;
  __syncthreads();
  lb[t] = ex;
  tail[t] = ex;
  __syncthreads();

#pragma unroll
  for (int k = 0; k < EPT; ++k) {
    if (bk[k] >= 0) {
      unsigned s = atomicAdd(&tail[bk[k]], 1u);
      stage[s] = make_uint2(pk[k], wv[k]);
      sbkt[s] = (unsigned char)bk[k];
    }
  }
  __syncthreads();

  // staged order is bucket-sorted: consecutive s -> consecutive global dest
  for (unsigned s = t; s < total; s += FBLK) {
    unsigned b = sbkt[s];
    uint2 v = stage[s];
    unsigned long long packed = (unsigned long long)v.x |
                                ((unsigned long long)v.y << 32);
    __builtin_nontemporal_store(packed,
        (unsigned long long*)&rec[gbase[b] + (s - lb[b])]);
  }
}

// ---------------- accumulate: one (bucket,part) per block ----------------
// mode 0: val = ew (weighted degree). mode 1: val = ew * bf16 p16[row].
__global__ __launch_bounds__(1024) void k_acc(const uint2* __restrict__ rec,
                                              const unsigned* __restrict__ hist,
                                              const unsigned short* __restrict__ p16,
                                              float* __restrict__ out,
                                              int mode, int split) {
  __shared__ float acc[BNODES];
  for (int i = threadIdx.x; i < BNODES; i += 1024) acc[i] = 0.f;
  __syncthreads();
  int b = blockIdx.x / split;
  int part = blockIdx.x - b * split;
  unsigned bs = hist[(size_t)b * NBLK];
  unsigned be = (b + 1 < NB) ? hist[(size_t)(b + 1) * NBLK] : (unsigned)N_EDGES;
  unsigned len = be - bs;
  unsigned s = bs + (unsigned)(((unsigned long long)len * part) / split);
  unsigned e = bs + (unsigned)(((unsigned long long)len * (part + 1)) / split);

  unsigned i = s + threadIdx.x;
  for (; i + 7u * 1024u < e; i += 8u * 1024u) {   // 8 records in flight
    unsigned long long r[8];
#pragma unroll
    for (int j = 0; j < 8; ++j)
      r[j] = __builtin_nontemporal_load(
          (const unsigned long long*)&rec[i + (unsigned)j * 1024u]);
    float v[8];
#pragma unroll
    for (int j = 0; j < 8; ++j) {
      v[j] = __uint_as_float((unsigned)(r[j] >> 32));
      if (mode) v[j] *= bf2f(p16[(unsigned)r[j] >> BSHIFT]);
    }
#pragma unroll
    for (int j = 0; j < 8; ++j)
      atomicAdd(&acc[(unsigned)r[j] & (BNODES - 1)], v[j]);
  }
  for (; i < e; i += 1024u) {
    unsigned long long r = __builtin_nontemporal_load(
        (const unsigned long long*)&rec[i]);
    float v = __uint_as_float((unsigned)(r >> 32));
    if (mode) v *= bf2f(p16[(unsigned)r >> BSHIFT]);
    atomicAdd(&acc[(unsigned)r & (BNODES - 1)], v);
  }
  __syncthreads();

  float* o = out + (size_t)part * N_NODES;
  int base = b * BNODES;
  for (int j = threadIdx.x; j < BNODES && base + j < N_NODES; j += 1024)
    o[base + j] = acc[j];
}

// ---------------- node-wise kernels ----------------

__global__ void k_dis_p(const float* __restrict__ x, const float* __restrict__ D,
                        float* __restrict__ A, unsigned short* __restrict__ P16,
                        int split) {
  int i = blockIdx.x * blockDim.x + threadIdx.x;
  if (i >= N_NODES) return;
  float deg = 1.0f;                       // self loop
  for (int j = 0; j < split; ++j) deg += D[(size_t)j * N_NODES + i];
  float d = rsqrtf(deg);
  A[i] = d;
  P16[i] = f2bf(d * x[i]);
}

__global__ void k_g2(const float* __restrict__ A, const float* __restrict__ x,
                     const float* __restrict__ D, unsigned short* __restrict__ P16,
                     const float* __restrict__ W1, const float* __restrict__ b1,
                     const float* __restrict__ W2, int split) {
  int i = blockIdx.x * blockDim.x + threadIdx.x;
  if (i >= N_NODES) return;
  float d = A[i];
  float sraw = 0.f;
  for (int j = 0; j < split; ++j) sraw += D[(size_t)j * N_NODES + i];
  float s1 = d * sraw + d * d * x[i];
  float g = 0.f;
#pragma unroll
  for (int j = 0; j < 4; ++j) {
    float h = fmaf(s1, W1[j], b1[j]);
    g = fmaf(fmaxf(h, 0.f), W2[j], g);
  }
  P16[i] = f2bf(d * g);
}

__global__ void k_out2(const float* __restrict__ A,
                       const unsigned short* __restrict__ P16,
                       const float* __restrict__ D, const float* __restrict__ b2,
                       const float* __restrict__ Wl, const float* __restrict__ bl,
                       float* __restrict__ y, int split) {
  int i = blockIdx.x * blockDim.x + threadIdx.x;
  if (i >= N_NODES) return;
  float d = A[i];
  float g = bf2f(P16[i]) / d;             // d in (0,1], safe
  float sraw = 0.f;
  for (int j = 0; j < split; ++j) sraw += D[(size_t)j * N_NODES + i];
  float agg2 = d * sraw + d * d * g;
  float v = fmaf(agg2 + b2[0], Wl[0], bl[0]);
  y[i] = 1.0f / (1.0f + expf(-v));
}

// ---------------- fallback (round-2 global-atomic path) ----------------

__global__ void f_deg(const int* __restrict__ col, const float* __restrict__ ew,
                      float* __restrict__ deg) {
  int i = blockIdx.x * blockDim.x + threadIdx.x;
  int stride = gridDim.x * blockDim.x;
  for (int e = i; e < N_EDGES; e += stride) atomicAdd(&deg[col[e]], ew[e]);
}
__global__ void f_dis(float* __restrict__ a) {
  int i = blockIdx.x * blockDim.x + threadIdx.x;
  if (i < N_NODES) a[i] = rsqrtf(a[i] + 1.0f);
}
__global__ void f_scatter(const int* __restrict__ row, const int* __restrict__ col,
                          const float* __restrict__ ew, const float* __restrict__ dis,
                          const float* __restrict__ src, float* __restrict__ acc) {
  int i = blockIdx.x * blockDim.x + threadIdx.x;
  int stride = gridDim.x * blockDim.x;
  for (int e = i; e < N_EDGES; e += stride) {
    int r = row[e]; int c = col[e];
    atomicAdd(&acc[c], dis[r] * ew[e] * src[r]);
  }
}
__global__ void f_g(const float* __restrict__ dis, const float* __restrict__ x,
                    float* __restrict__ s1g, const float* __restrict__ W1,
                    const float* __restrict__ b1, const float* __restrict__ W2) {
  int i = blockIdx.x * blockDim.x + threadIdx.x;
  if (i >= N_NODES) return;
  float d = dis[i];
  float s1 = d * s1g[i] + d * d * x[i];
  float g = 0.f;
#pragma unroll
  for (int j = 0; j < 4; ++j) {
    float h = fmaf(s1, W1[j], b1[j]);
    g = fmaf(fmaxf(h, 0.f), W2[j], g);
  }
  s1g[i] = g;
}
__global__ void f_out(const float* __restrict__ dis, const float* __restrict__ g,
                      float* __restrict__ s2out, const float* __restrict__ b2,
                      const float* __restrict__ Wl, const float* __restrict__ bl) {
  int i = blockIdx.x * blockDim.x + threadIdx.x;
  if (i >= N_NODES) return;
  float d = dis[i];
  float agg2 = d * s2out[i] + d * d * g[i];
  float v = fmaf(agg2 + b2[0], Wl[0], bl[0]);
  s2out[i] = 1.0f / (1.0f + expf(-v));
}

// ---------------- launch ----------------

extern "C" void kernel_launch(void* const* d_in, const int* in_sizes, int n_in,
                              void* d_out, int out_size, void* d_ws, size_t ws_size,
                              hipStream_t stream) {
  const float* x  = (const float*)d_in[0];
  const int* ei   = (const int*)d_in[1];   // int32 (harness narrows int64)
  const float* ew = (const float*)d_in[2];
  const float* W1 = (const float*)d_in[3];
  const float* b1 = (const float*)d_in[4];
  const float* W2 = (const float*)d_in[5];
  const float* b2 = (const float*)d_in[6];
  const float* Wl = (const float*)d_in[7];
  const float* bl = (const float*)d_in[8];

  const int* row = ei;
  const int* col = ei + N_EDGES;

  const size_t REC_B   = (size_t)N_EDGES * 8;          // 134,217,728
  const size_t HIST_B  = (size_t)NHIST_PAD * 4;        // 5,107,712
  const size_t HISTT_B = (size_t)NBLK * 256 * 4;       // 5,334,016
  const size_t BSUM_B  = 8192;                         // >= NSCAN*4
  const size_t NODE_B  = (size_t)N_NODES * 4;
  const size_t P16_B   = 2000128;                      // 2MB, 16B-aligned pad
  const size_t FIXED   = REC_B + HIST_B + HISTT_B + BSUM_B + NODE_B + P16_B;

  dim3 blk(256);
  dim3 ngrid((N_NODES + 255) / 256);
  dim3 tgrid((NBLK + 31) / 32, 8);
  dim3 tblk(32, 32);

  int split = 0;
  for (int s : {2, 1})
    if (ws_size >= FIXED + (size_t)s * NODE_B) { split = s; break; }

  if (split) {
    char* w = (char*)d_ws;
    uint2* rec          = (uint2*)w;
    unsigned* hist      = (unsigned*)(w + REC_B);
    unsigned* histT     = (unsigned*)(w + REC_B + HIST_B);     // also histT2
    unsigned* bsum      = (unsigned*)(w + REC_B + HIST_B + HISTT_B);
    float* A            = (float*)(w + REC_B + HIST_B + HISTT_B + BSUM_B);
    unsigned short* P16 = (unsigned short*)(A + N_NODES);
    float* D            = (float*)((char*)P16 + P16_B);

    // zero the scan pad tail (rest of hist fully written by k_t1)
    hipMemsetAsync(hist + NHIST, 0, (size_t)(NHIST_PAD - NHIST) * 4, stream);

    k_count<<<NBLK, FBLK, 0, stream>>>(col, histT);
    k_t1   <<<tgrid, tblk, 0, stream>>>(histT, hist);
    k_scanA<<<NSCAN, SCAN_TPB, 0, stream>>>(hist, bsum);
    k_scanB<<<1, 1024, 0, stream>>>(bsum);
    k_scanC<<<NSCAN, SCAN_TPB, 0, stream>>>(hist, bsum);
    k_t2   <<<tgrid, tblk, 0, stream>>>(hist, histT);          // offsets, transposed
    k_fill <<<NBLK, FBLK, 0, stream>>>(row, col, ew, histT, rec);

    k_acc  <<<NB * split, 1024, 0, stream>>>(rec, hist, nullptr, D, 0, split);
    k_dis_p<<<ngrid, blk, 0, stream>>>(x, D, A, P16, split);
    k_acc  <<<NB * split, 1024, 0, stream>>>(rec, hist, P16, D, 1, split);
    k_g2   <<<ngrid, blk, 0, stream>>>(A, x, D, P16, W1, b1, W2, split);
    k_acc  <<<NB * split, 1024, 0, stream>>>(rec, hist, P16, D, 1, split);
    k_out2 <<<ngrid, blk, 0, stream>>>(A, P16, D, b2, Wl, bl, (float*)d_out, split);
  } else {
    float* Aw = (float*)d_ws;
    float* Bw = Aw + N_NODES;
    float* Cw = (float*)d_out;
    hipMemsetAsync(d_ws, 0, 2ull * NODE_B, stream);
    hipMemsetAsync(d_out, 0, NODE_B, stream);
    dim3 egrid(4096);
    f_deg<<<egrid, blk, 0, stream>>>(col, ew, Aw);
    f_dis<<<ngrid, blk, 0, stream>>>(Aw);
    f_scatter<<<egrid, blk, 0, stream>>>(row, col, ew, Aw, x, Bw);
    f_g<<<ngrid, blk, 0, stream>>>(Aw, x, Bw, W1, b1, W2);
    f_scatter<<<egrid, blk, 0, stream>>>(row, col, ew, Aw, Bw, Cw);
    f_out<<<ngrid, blk, 0, stream>>>(Aw, Bw, Cw, b2, Wl, bl);
  }
}

// Round 7
// 475.805 us; speedup vs baseline: 1.1397x; 1.0415x over previous
//
#include <hip/hip_runtime.h>

// GCN on 1M nodes / 16M edges, collapsed to scalar per-node features.
//
//   deg[c]  = sum_{e: col=c} ew[e] + 1 (self loop)
//   dis     = rsqrt(deg)
//   S1[c]   = dis[c] * (sum_e dis[row]*ew*x[row]) + dis[c]^2 * x[c]
//   g[c]    = sum_j relu(S1[c]*W1[j] + b1[j]) * W2[j]
//   S2[c]   = dis[c] * (sum_e dis[row]*ew*g[row]) + dis[c]^2 * g[c]
//   y[c]    = sigmoid((S2[c]+b2)*Wl + bl)
//
// R6 post-mortem: nontemporal stores in k_fill's writeout cost ~45us (L2
// write-combining bypassed; plain stores R4=120us vs nt R5/R6=160us, same
// WRITE_SIZE). k_acc at 1024thr/split2 = 490 blocks -> 2-round schedule with
// half the CUs idle in round 2.
// R7: plain uint2 stores in fill; k_acc 512thr/split4 = 980 blocks (4/CU).

constexpr int N_NODES = 1000000;
constexpr int N_EDGES = 16000000;

constexpr int BSHIFT = 12;
constexpr int BNODES = 1 << BSHIFT;                    // 4096 nodes/bucket
constexpr int NB = (N_NODES + BNODES - 1) / BNODES;    // 245 buckets
constexpr int EPT = 12;                                // edges/thread in count+fill
constexpr int FBLK = 256;
constexpr int CHUNK = FBLK * EPT;                      // 3072 edges/block
constexpr int NBLK = (N_EDGES + CHUNK - 1) / CHUNK;    // 5209
constexpr int NHIST = NB * NBLK;                       // 1,276,205
constexpr int SCAN_TPB = 256;
constexpr int SCAN_EPB = 1024;
constexpr int NSCAN = (NHIST + SCAN_EPB - 1) / SCAN_EPB;  // 1247
constexpr int NHIST_PAD = NSCAN * SCAN_EPB;            // 1,276,928

__device__ inline unsigned short f2bf(float f) {   // fp32 -> bf16 RNE
  unsigned u = __float_as_uint(f);
  return (unsigned short)((u + 0x7FFFu + ((u >> 16) & 1u)) >> 16);
}
__device__ inline float bf2f(unsigned short h) {
  return __uint_as_float((unsigned)h << 16);
}

// ---------------- build: count / transpose / scan / transpose / fill --------

// histT layout [NBLK][256]: block writes its own contiguous row (coalesced).
__global__ __launch_bounds__(FBLK) void k_count(const int* __restrict__ col,
                                                unsigned* __restrict__ histT) {
  __shared__ unsigned cnt[256];
  int t = threadIdx.x;
  cnt[t] = 0;
  __syncthreads();
  int e0 = blockIdx.x * CHUNK;
#pragma unroll
  for (int k = 0; k < EPT; ++k) {
    int e = e0 + k * FBLK + t;
    if (e < N_EDGES) atomicAdd(&cnt[col[e] >> BSHIFT], 1u);
  }
  __syncthreads();
  histT[(size_t)blockIdx.x * 256 + t] = cnt[t];
}

// histT[NBLK][256] -> hist[b*NBLK + blk] (bucket-major flat, for linear scan)
__global__ __launch_bounds__(1024) void k_t1(const unsigned* __restrict__ in,
                                             unsigned* __restrict__ out) {
  __shared__ unsigned tile[32][33];
  int bx = blockIdx.x * 32;   // blk base
  int by = blockIdx.y * 32;   // b base
  int tx = threadIdx.x, ty = threadIdx.y;
  int rblk = bx + ty;
  if (rblk < NBLK) tile[ty][tx] = in[(size_t)rblk * 256 + by + tx];
  __syncthreads();
  int wb = by + ty, wblk = bx + tx;
  if (wb < NB && wblk < NBLK) out[(size_t)wb * NBLK + wblk] = tile[tx][ty];
}

// hist offsets (bucket-major) -> histT2[blk*256 + b] (fill reads coalesced)
__global__ __launch_bounds__(1024) void k_t2(const unsigned* __restrict__ in,
                                             unsigned* __restrict__ out) {
  __shared__ unsigned tile[32][33];
  int bx = blockIdx.x * 32;   // blk base
  int by = blockIdx.y * 32;   // b base
  int tx = threadIdx.x, ty = threadIdx.y;
  int rb = by + ty, rblk = bx + tx;
  if (rb < NB && rblk < NBLK) tile[ty][tx] = in[(size_t)rb * NBLK + rblk];
  __syncthreads();
  int wblk = bx + ty, wb = by + tx;
  if (wblk < NBLK && wb < NB) out[(size_t)wblk * 256 + wb] = tile[tx][ty];
}

__global__ __launch_bounds__(SCAN_TPB) void k_scanA(unsigned* __restrict__ h,
                                                    unsigned* __restrict__ bsum) {
  __shared__ unsigned sc[SCAN_TPB];
  int t = threadIdx.x;
  size_t base = (size_t)blockIdx.x * SCAN_EPB + (size_t)t * 4;
  uint4 v = *(const uint4*)(h + base);
  unsigned s = v.x + v.y + v.z + v.w;
  sc[t] = s;
  __syncthreads();
  for (int d = 1; d < SCAN_TPB; d <<= 1) {
    unsigned u = (t >= d) ? sc[t - d] : 0;
    __syncthreads();
    sc[t] += u;
    __syncthreads();
  }
  unsigned ex = sc[t] - s;
  uint4 o;
  o.x = ex; o.y = ex + v.x; o.z = ex + v.x + v.y; o.w = ex + v.x + v.y + v.z;
  *(uint4*)(h + base) = o;
  if (t == SCAN_TPB - 1) bsum[blockIdx.x] = sc[t];
}

__global__ __launch_bounds__(1024) void k_scanB(unsigned* __restrict__ bsum) {
  __shared__ unsigned sc[1024];
  int t = threadIdx.x;
  unsigned a0 = (2 * t < NSCAN) ? bsum[2 * t] : 0;
  unsigned a1 = (2 * t + 1 < NSCAN) ? bsum[2 * t + 1] : 0;
  unsigned s = a0 + a1;
  sc[t] = s;
  __syncthreads();
  for (int d = 1; d < 1024; d <<= 1) {
    unsigned u = (t >= d) ? sc[t - d] : 0;
    __syncthreads();
    sc[t] += u;
    __syncthreads();
  }
  unsigned ex = sc[t] - s;
  if (2 * t < NSCAN) bsum[2 * t] = ex;
  if (2 * t + 1 < NSCAN) bsum[2 * t + 1] = ex + a0;
}

__global__ __launch_bounds__(SCAN_TPB) void k_scanC(unsigned* __restrict__ h,
                                                    const unsigned* __restrict__ bsum) {
  unsigned add = bsum[blockIdx.x];
  size_t base = (size_t)blockIdx.x * SCAN_EPB + (size_t)threadIdx.x * 4;
  uint4 v = *(uint4*)(h + base);
  v.x += add; v.y += add; v.z += add; v.w += add;
  *(uint4*)(h + base) = v;
}

// Register-stash + LDS-reorder fill: coalesced record writes (plain stores —
// L2 write-combining absorbs the short per-bucket runs; nt stores cost +45us).
// record = (row<<12 | col&0xFFF, bits(ew)); row < 2^20 fits.
__global__ __launch_bounds__(FBLK) void k_fill(const int* __restrict__ row,
                                               const int* __restrict__ col,
                                               const float* __restrict__ ew,
                                               const unsigned* __restrict__ histT2,
                                               uint2* __restrict__ rec) {
  __shared__ unsigned lhist[256];
  __shared__ unsigned lb[256];
  __shared__ unsigned tail[256];
  __shared__ unsigned gbase[NB];
  __shared__ uint2 stage[CHUNK];
  __shared__ unsigned char sbkt[CHUNK];

  int t = threadIdx.x;
  int blk = blockIdx.x;
  lhist[t] = 0;
  for (int i = t; i < NB; i += FBLK)
    gbase[i] = histT2[(size_t)blk * 256 + i];          // coalesced row read
  __syncthreads();

  int e0 = blk * CHUNK;
  unsigned pk[EPT], wv[EPT];
  int bk[EPT];
#pragma unroll
  for (int k = 0; k < EPT; ++k) {
    int e = e0 + k * FBLK + t;
    bk[k] = -1;
    if (e < N_EDGES) {
      int c = col[e];
      pk[k] = ((unsigned)row[e] << BSHIFT) | (unsigned)(c & (BNODES - 1));
      wv[k] = __float_as_uint(ew[e]);
      bk[k] = c >> BSHIFT;
      atomicAdd(&lhist[bk[k]], 1u);
    }
  }
  __syncthreads();

  unsigned own = lhist[t];
  lb[t] = own;
  __syncthreads();
  for (int d = 1; d < 256; d <<= 1) {   // Hillis-Steele inclusive
    unsigned u = (t >= d) ? lb[t - d] : 0;
    __syncthreads();
    lb[t] += u;
    __syncthreads();
  }
  unsigned total = lb[255];
  unsigned ex = lb[t] - own;
  __syncthreads();
  lb[t] = ex;
  tail[t] = ex;
  __syncthreads();

#pragma unroll
  for (int k = 0; k < EPT; ++k) {
    if (bk[k] >= 0) {
      unsigned s = atomicAdd(&tail[bk[k]], 1u);
      stage[s] = make_uint2(pk[k], wv[k]);
      sbkt[s] = (unsigned char)bk[k];
    }
  }
  __syncthreads();

  // staged order is bucket-sorted: consecutive s -> consecutive global dest
  for (unsigned s = t; s < total; s += FBLK) {
    unsigned b = sbkt[s];
    rec[gbase[b] + (s - lb[b])] = stage[s];
  }
}

// ---------------- accumulate: one (bucket,part) per block ----------------
// mode 0: val = ew (weighted degree). mode 1: val = ew * bf16 p16[row].
// 512 threads, split=4 -> 980 blocks, 4 co-resident blocks/CU (balance).
__global__ __launch_bounds__(512) void k_acc(const uint2* __restrict__ rec,
                                             const unsigned* __restrict__ hist,
                                             const unsigned short* __restrict__ p16,
                                             float* __restrict__ out,
                                             int mode, int split) {
  __shared__ float acc[BNODES];
  for (int i = threadIdx.x; i < BNODES; i += 512) acc[i] = 0.f;
  __syncthreads();
  int b = blockIdx.x / split;
  int part = blockIdx.x - b * split;
  unsigned bs = hist[(size_t)b * NBLK];
  unsigned be = (b + 1 < NB) ? hist[(size_t)(b + 1) * NBLK] : (unsigned)N_EDGES;
  unsigned len = be - bs;
  unsigned s = bs + (unsigned)(((unsigned long long)len * part) / split);
  unsigned e = bs + (unsigned)(((unsigned long long)len * (part + 1)) / split);

  unsigned i = s + threadIdx.x;
  for (; i + 7u * 512u < e; i += 8u * 512u) {   // 8 records in flight
    unsigned long long r[8];
#pragma unroll
    for (int j = 0; j < 8; ++j)
      r[j] = __builtin_nontemporal_load(
          (const unsigned long long*)&rec[i + (unsigned)j * 512u]);
    float v[8];
#pragma unroll
    for (int j = 0; j < 8; ++j) {
      v[j] = __uint_as_float((unsigned)(r[j] >> 32));
      if (mode) v[j] *= bf2f(p16[(unsigned)r[j] >> BSHIFT]);
    }
#pragma unroll
    for (int j = 0; j < 8; ++j)
      atomicAdd(&acc[(unsigned)r[j] & (BNODES - 1)], v[j]);
  }
  for (; i < e; i += 512u) {
    unsigned long long r = __builtin_nontemporal_load(
        (const unsigned long long*)&rec[i]);
    float v = __uint_as_float((unsigned)(r >> 32));
    if (mode) v *= bf2f(p16[(unsigned)r >> BSHIFT]);
    atomicAdd(&acc[(unsigned)r & (BNODES - 1)], v);
  }
  __syncthreads();

  float* o = out + (size_t)part * N_NODES;
  int base = b * BNODES;
  for (int j = threadIdx.x; j < BNODES && base + j < N_NODES; j += 512)
    o[base + j] = acc[j];
}

// ---------------- node-wise kernels ----------------

__global__ void k_dis_p(const float* __restrict__ x, const float* __restrict__ D,
                        float* __restrict__ A, unsigned short* __restrict__ P16,
                        int split) {
  int i = blockIdx.x * blockDim.x + threadIdx.x;
  if (i >= N_NODES) return;
  float deg = 1.0f;                       // self loop
  for (int j = 0; j < split; ++j) deg += D[(size_t)j * N_NODES + i];
  float d = rsqrtf(deg);
  A[i] = d;
  P16[i] = f2bf(d * x[i]);
}

__global__ void k_g2(const float* __restrict__ A, const float* __restrict__ x,
                     const float* __restrict__ D, unsigned short* __restrict__ P16,
                     const float* __restrict__ W1, const float* __restrict__ b1,
                     const float* __restrict__ W2, int split) {
  int i = blockIdx.x * blockDim.x + threadIdx.x;
  if (i >= N_NODES) return;
  float d = A[i];
  float sraw = 0.f;
  for (int j = 0; j < split; ++j) sraw += D[(size_t)j * N_NODES + i];
  float s1 = d * sraw + d * d * x[i];
  float g = 0.f;
#pragma unroll
  for (int j = 0; j < 4; ++j) {
    float h = fmaf(s1, W1[j], b1[j]);
    g = fmaf(fmaxf(h, 0.f), W2[j], g);
  }
  P16[i] = f2bf(d * g);
}

__global__ void k_out2(const float* __restrict__ A,
                       const unsigned short* __restrict__ P16,
                       const float* __restrict__ D, const float* __restrict__ b2,
                       const float* __restrict__ Wl, const float* __restrict__ bl,
                       float* __restrict__ y, int split) {
  int i = blockIdx.x * blockDim.x + threadIdx.x;
  if (i >= N_NODES) return;
  float d = A[i];
  float g = bf2f(P16[i]) / d;             // d in (0,1], safe
  float sraw = 0.f;
  for (int j = 0; j < split; ++j) sraw += D[(size_t)j * N_NODES + i];
  float agg2 = d * sraw + d * d * g;
  float v = fmaf(agg2 + b2[0], Wl[0], bl[0]);
  y[i] = 1.0f / (1.0f + expf(-v));
}

// ---------------- fallback (round-2 global-atomic path) ----------------

__global__ void f_deg(const int* __restrict__ col, const float* __restrict__ ew,
                      float* __restrict__ deg) {
  int i = blockIdx.x * blockDim.x + threadIdx.x;
  int stride = gridDim.x * blockDim.x;
  for (int e = i; e < N_EDGES; e += stride) atomicAdd(&deg[col[e]], ew[e]);
}
__global__ void f_dis(float* __restrict__ a) {
  int i = blockIdx.x * blockDim.x + threadIdx.x;
  if (i < N_NODES) a[i] = rsqrtf(a[i] + 1.0f);
}
__global__ void f_scatter(const int* __restrict__ row, const int* __restrict__ col,
                          const float* __restrict__ ew, const float* __restrict__ dis,
                          const float* __restrict__ src, float* __restrict__ acc) {
  int i = blockIdx.x * blockDim.x + threadIdx.x;
  int stride = gridDim.x * blockDim.x;
  for (int e = i; e < N_EDGES; e += stride) {
    int r = row[e]; int c = col[e];
    atomicAdd(&acc[c], dis[r] * ew[e] * src[r]);
  }
}
__global__ void f_g(const float* __restrict__ dis, const float* __restrict__ x,
                    float* __restrict__ s1g, const float* __restrict__ W1,
                    const float* __restrict__ b1, const float* __restrict__ W2) {
  int i = blockIdx.x * blockDim.x + threadIdx.x;
  if (i >= N_NODES) return;
  float d = dis[i];
  float s1 = d * s1g[i] + d * d * x[i];
  float g = 0.f;
#pragma unroll
  for (int j = 0; j < 4; ++j) {
    float h = fmaf(s1, W1[j], b1[j]);
    g = fmaf(fmaxf(h, 0.f), W2[j], g);
  }
  s1g[i] = g;
}
__global__ void f_out(const float* __restrict__ dis, const float* __restrict__ g,
                      float* __restrict__ s2out, const float* __restrict__ b2,
                      const float* __restrict__ Wl, const float* __restrict__ bl) {
  int i = blockIdx.x * blockDim.x + threadIdx.x;
  if (i >= N_NODES) return;
  float d = dis[i];
  float agg2 = d * s2out[i] + d * d * g[i];
  float v = fmaf(agg2 + b2[0], Wl[0], bl[0]);
  s2out[i] = 1.0f / (1.0f + expf(-v));
}

// ---------------- launch ----------------

extern "C" void kernel_launch(void* const* d_in, const int* in_sizes, int n_in,
                              void* d_out, int out_size, void* d_ws, size_t ws_size,
                              hipStream_t stream) {
  const float* x  = (const float*)d_in[0];
  const int* ei   = (const int*)d_in[1];   // int32 (harness narrows int64)
  const float* ew = (const float*)d_in[2];
  const float* W1 = (const float*)d_in[3];
  const float* b1 = (const float*)d_in[4];
  const float* W2 = (const float*)d_in[5];
  const float* b2 = (const float*)d_in[6];
  const float* Wl = (const float*)d_in[7];
  const float* bl = (const float*)d_in[8];

  const int* row = ei;
  const int* col = ei + N_EDGES;

  const size_t REC_B   = (size_t)N_EDGES * 8;          // 134,217,728
  const size_t HIST_B  = (size_t)NHIST_PAD * 4;        // 5,107,712
  const size_t HISTT_B = (size_t)NBLK * 256 * 4;       // 5,334,016
  const size_t BSUM_B  = 8192;                         // >= NSCAN*4
  const size_t NODE_B  = (size_t)N_NODES * 4;
  const size_t P16_B   = 2000128;                      // 2MB, 16B-aligned pad
  const size_t FIXED   = REC_B + HIST_B + HISTT_B + BSUM_B + NODE_B + P16_B;

  dim3 blk(256);
  dim3 ngrid((N_NODES + 255) / 256);
  dim3 tgrid((NBLK + 31) / 32, 8);
  dim3 tblk(32, 32);

  int split = 0;
  for (int s : {4, 2, 1})
    if (ws_size >= FIXED + (size_t)s * NODE_B) { split = s; break; }

  if (split) {
    char* w = (char*)d_ws;
    uint2* rec          = (uint2*)w;
    unsigned* hist      = (unsigned*)(w + REC_B);
    unsigned* histT     = (unsigned*)(w + REC_B + HIST_B);     // also histT2
    unsigned* bsum      = (unsigned*)(w + REC_B + HIST_B + HISTT_B);
    float* A            = (float*)(w + REC_B + HIST_B + HISTT_B + BSUM_B);
    unsigned short* P16 = (unsigned short*)(A + N_NODES);
    float* D            = (float*)((char*)P16 + P16_B);

    // zero the scan pad tail (rest of hist fully written by k_t1)
    hipMemsetAsync(hist + NHIST, 0, (size_t)(NHIST_PAD - NHIST) * 4, stream);

    k_count<<<NBLK, FBLK, 0, stream>>>(col, histT);
    k_t1   <<<tgrid, tblk, 0, stream>>>(histT, hist);
    k_scanA<<<NSCAN, SCAN_TPB, 0, stream>>>(hist, bsum);
    k_scanB<<<1, 1024, 0, stream>>>(bsum);
    k_scanC<<<NSCAN, SCAN_TPB, 0, stream>>>(hist, bsum);
    k_t2   <<<tgrid, tblk, 0, stream>>>(hist, histT);          // offsets, transposed
    k_fill <<<NBLK, FBLK, 0, stream>>>(row, col, ew, histT, rec);

    k_acc  <<<NB * split, 512, 0, stream>>>(rec, hist, nullptr, D, 0, split);
    k_dis_p<<<ngrid, blk, 0, stream>>>(x, D, A, P16, split);
    k_acc  <<<NB * split, 512, 0, stream>>>(rec, hist, P16, D, 1, split);
    k_g2   <<<ngrid, blk, 0, stream>>>(A, x, D, P16, W1, b1, W2, split);
    k_acc  <<<NB * split, 512, 0, stream>>>(rec, hist, P16, D, 1, split);
    k_out2 <<<ngrid, blk, 0, stream>>>(A, P16, D, b2, Wl, bl, (float*)d_out, split);
  } else {
    float* Aw = (float*)d_ws;
    float* Bw = Aw + N_NODES;
    float* Cw = (float*)d_out;
    hipMemsetAsync(d_ws, 0, 2ull * NODE_B, stream);
    hipMemsetAsync(d_out, 0, NODE_B, stream);
    dim3 egrid(4096);
    f_deg<<<egrid, blk, 0, stream>>>(col, ew, Aw);
    f_dis<<<ngrid, blk, 0, stream>>>(Aw);
    f_scatter<<<egrid, blk, 0, stream>>>(row, col, ew, Aw, x, Bw);
    f_g<<<ngrid, blk, 0, stream>>>(Aw, x, Bw, W1, b1, W2);
    f_scatter<<<egrid, blk, 0, stream>>>(row, col, ew, Aw, Bw, Cw);
    f_out<<<ngrid, blk, 0, stream>>>(Aw, Bw, Cw, b2, Wl, bl);
  }
}